// Round 5
// baseline (122.676 us; speedup 1.0000x reference)
//
#include <hip/hip_runtime.h>
#include <hip/hip_bf16.h>

typedef __bf16 bf16x8 __attribute__((ext_vector_type(8)));
typedef float  f32x16 __attribute__((ext_vector_type(16)));

#define N_TOT  8192
#define B_HALF 4096
#define D      256
// exp(sim) = exp(10*dot) = exp2(dot * 10*log2(e));  prescale zn by sqrt(10*log2(e))
// so the MFMA dot directly yields the exp2 argument.
#define SQK1   3.79828254f
#define LN2    0.6931471805599453f

#define RB      256   // rows per block (4 waves x 64)
#define WROWS   64    // rows per wave (2 rowtiles of 32)
#define CB      32    // cols per LDS stage
#define SLICE   512   // cols per block
#define NSLICE  16
#define NSTAGE  16    // SLICE/CB
#define LDS_RS  264   // padded LDS row stride in bf16 (528B): b128 quad = (c32+hi)%8 -> conflict-free

// ---------------- kernel 1: concat + L2-normalize -> bf16 (prescaled) ----------------
__global__ __launch_bounds__(256) void normalize_kernel(
    const float* __restrict__ zi, const float* __restrict__ zj,
    ushort* __restrict__ zn, float* __restrict__ out)
{
    if (blockIdx.x == 0 && threadIdx.x == 0) *out = 0.0f;   // zero accumulator (stream-ordered)
    int row  = (blockIdx.x * 256 + threadIdx.x) >> 6;       // one wave per row
    int lane = threadIdx.x & 63;
    const float* src = (row < B_HALF) ? (zi + (size_t)row * D)
                                      : (zj + (size_t)(row - B_HALF) * D);
    float4 v = ((const float4*)src)[lane];
    float ss = v.x * v.x + v.y * v.y + v.z * v.z + v.w * v.w;
    #pragma unroll
    for (int m = 1; m < 64; m <<= 1) ss += __shfl_xor(ss, m);
    float r = SQK1 / fmaxf(sqrtf(ss), 1e-8f);               // fold exp2-scale into data
    union { ushort4 u4; __hip_bfloat16 h[4]; } o;
    o.h[0] = __float2bfloat16(v.x * r);
    o.h[1] = __float2bfloat16(v.y * r);
    o.h[2] = __float2bfloat16(v.z * r);
    o.h[3] = __float2bfloat16(v.w * r);
    ((ushort4*)zn)[(size_t)row * (D / 4) + lane] = o.u4;
}

// ---------------- kernel 2: fused sim + sum-of-exp ----------------
// grid (32,16): x = 256-row block, y = 512-col slice. 4 waves, 64 rows/wave.
// 2 independent blocks/CU -> barriers desynchronize, MFMA pipe stays fed (m114).
// A (64 rows x K=256) hoisted in VGPRs -> each LDS B-frag read feeds 2 MFMAs.
// Per-SIMD per-stage budget: MFMA 2x32x~32cyc ~ 2067 > LDS-read 384 + exp ~512 (hidden).
__global__ __launch_bounds__(256, 2) void fused_kernel(
    const ushort* __restrict__ zn,
    float* __restrict__ spartial,   // [N_TOT][NSLICE]
    float* __restrict__ posdot)     // [N_TOT] prescaled dot (= 10*log2(e)*cos)
{
    __shared__ ushort lds[2][CB * LDS_RS];   // 2 x 16896 B

    int tid  = threadIdx.x;
    int lane = tid & 63;
    int w    = tid >> 6;             // 0..3
    int hi   = lane >> 5;            // 0/1
    int c32  = lane & 31;
    int r0   = blockIdx.x * RB + w * WROWS;
    int cs0  = blockIdx.y * SLICE;

    // hoist A: 64 rows x K=256 (2 rowtiles x 16 k-steps x bf16x8) = 128 VGPR
    bf16x8 a[2][16];
    #pragma unroll
    for (int rt = 0; rt < 2; ++rt) {
        const ushort* ar = zn + (size_t)(r0 + rt * 32 + c32) * D + hi * 8;
        #pragma unroll
        for (int ks = 0; ks < 16; ++ks)
            a[rt][ks] = *(const bf16x8*)(ar + ks * 16);
    }

    float srow[2][16];
    #pragma unroll
    for (int rt = 0; rt < 2; ++rt)
        #pragma unroll
        for (int g = 0; g < 16; ++g) srow[rt][g] = 0.f;

    // stage 0: global -> regs -> LDS  (32 cols x 32 k-chunks = 1024 chunks / 256 thr)
    uint4 st[4];
    #pragma unroll
    for (int i = 0; i < 4; ++i) {
        int chunk = tid + i * 256;
        st[i] = *(const uint4*)(zn + (size_t)(cs0 + (chunk >> 5)) * D + (chunk & 31) * 8);
    }
    #pragma unroll
    for (int i = 0; i < 4; ++i) {
        int chunk = tid + i * 256;
        *(uint4*)(&lds[0][(chunk >> 5) * LDS_RS + (chunk & 31) * 8]) = st[i];
    }
    __syncthreads();

    for (int s = 0; s < NSTAGE; ++s) {
        int cur = s & 1;
        if (s + 1 < NSTAGE) {        // issue next stage's loads early (hide L2 latency under MFMA)
            #pragma unroll
            for (int i = 0; i < 4; ++i) {
                int chunk = tid + i * 256;
                st[i] = *(const uint4*)(zn + (size_t)(cs0 + (s + 1) * CB + (chunk >> 5)) * D + (chunk & 31) * 8);
            }
        }

        f32x16 acc0 = {};
        f32x16 acc1 = {};
        const ushort* bbase = &lds[cur][(size_t)c32 * LDS_RS + hi * 8];
        __builtin_amdgcn_s_setprio(1);           // T5: favor MFMA-issuing waves
        #pragma unroll
        for (int ks = 0; ks < 16; ++ks) {
            bf16x8 b = *(const bf16x8*)(bbase + ks * 16);
            acc0 = __builtin_amdgcn_mfma_f32_32x32x16_bf16(a[0][ks], b, acc0, 0, 0, 0);
            acc1 = __builtin_amdgcn_mfma_f32_32x32x16_bf16(a[1][ks], b, acc1, 0, 0, 0);
        }
        __builtin_amdgcn_s_setprio(0);

        int colbase = cs0 + s * CB;
        #pragma unroll
        for (int rt = 0; rt < 2; ++rt) {
            const f32x16& acc = (rt == 0) ? acc0 : acc1;
            int rowbase = r0 + rt * 32;
            bool isdiag = (rowbase == colbase);
            bool ispos  = ((rowbase ^ B_HALF) == colbase);   // (i+B)%N == i^B for pow2
            if (isdiag) {
                #pragma unroll
                for (int g = 0; g < 16; ++g) {
                    int rl = (g & 3) + 8 * (g >> 2) + 4 * hi;   // C-row (m74/m101)
                    float e = exp2f(acc[g]);
                    srow[rt][g] += (rl != c32) ? e : 0.0f;      // mask self-sim
                }
            } else if (ispos) {
                #pragma unroll
                for (int g = 0; g < 16; ++g) {
                    int rl = (g & 3) + 8 * (g >> 2) + 4 * hi;
                    if (rl == c32) posdot[rowbase + rl] = acc[g];  // unique writer/row
                    srow[rt][g] += exp2f(acc[g]);
                }
            } else {
                #pragma unroll
                for (int g = 0; g < 16; ++g)
                    srow[rt][g] += exp2f(acc[g]);
            }
        }

        if (s + 1 < NSTAGE) {
            __syncthreads();         // all waves done reading lds[cur^1] (stage s-1) and lds[cur]
            #pragma unroll
            for (int i = 0; i < 4; ++i) {
                int chunk = tid + i * 256;
                *(uint4*)(&lds[cur ^ 1][(chunk >> 5) * LDS_RS + (chunk & 31) * 8]) = st[i];
            }
            __syncthreads();
        }
    }

    // reduce each row's partials over the 32 column-slots (xor-shuffle within 32-lane half)
    #pragma unroll
    for (int rt = 0; rt < 2; ++rt) {
        #pragma unroll
        for (int g = 0; g < 16; ++g) {
            float v = srow[rt][g];
            v += __shfl_xor(v, 1);
            v += __shfl_xor(v, 2);
            v += __shfl_xor(v, 4);
            v += __shfl_xor(v, 8);
            v += __shfl_xor(v, 16);
            if (c32 == 0) {
                int rl = (g & 3) + 8 * (g >> 2) + 4 * hi;
                spartial[(size_t)(r0 + rt * 32 + rl) * NSLICE + blockIdx.y] = v;
            }
        }
    }
}

// ---------------- kernel 3: finalize ----------------
__global__ __launch_bounds__(256) void finalize_kernel(
    const float* __restrict__ spartial, const float* __restrict__ posdot,
    float* __restrict__ out)
{
    int i    = blockIdx.x * 256 + threadIdx.x;   // row 0..8191
    int lane = threadIdx.x & 63;
    int wv   = threadIdx.x >> 6;
    float ssum = 0.f;
    #pragma unroll
    for (int k = 0; k < NSLICE; ++k) ssum += spartial[(size_t)i * NSLICE + k];
    // loss_i = ln(sum_{j!=i} exp(sim_ij)) - 10*cos_pos = LN2*(log2(ssum) - posdot_scaled)
    float loss = LN2 * (log2f(ssum) - posdot[i]);
    #pragma unroll
    for (int m = 1; m < 64; m <<= 1) loss += __shfl_xor(loss, m);
    __shared__ float red[4];
    if (lane == 0) red[wv] = loss;
    __syncthreads();
    if (threadIdx.x == 0) {
        float t = red[0] + red[1] + red[2] + red[3];
        atomicAdd(out, t * (1.0f / (float)N_TOT));
    }
}

extern "C" void kernel_launch(void* const* d_in, const int* in_sizes, int n_in,
                              void* d_out, int out_size, void* d_ws, size_t ws_size,
                              hipStream_t stream)
{
    const float* zi = (const float*)d_in[0];
    const float* zj = (const float*)d_in[1];
    float* out = (float*)d_out;

    ushort* zn       = (ushort*)d_ws;                                             // 4 MiB
    float*  posdot   = (float*)((char*)d_ws + (size_t)N_TOT * D * 2);             // 32 KiB
    float*  spartial = (float*)((char*)d_ws + (size_t)N_TOT * D * 2 + N_TOT * 4); // 512 KiB

    normalize_kernel<<<N_TOT / 4, 256, 0, stream>>>(zi, zj, zn, out);

    dim3 grid2(N_TOT / RB, NSLICE);
    fused_kernel<<<grid2, 256, 0, stream>>>(zn, spartial, posdot);

    finalize_kernel<<<N_TOT / 256, 256, 0, stream>>>(spartial, posdot, out);
}